// Round 5
// baseline (725412.500 us; speedup 1.0000x reference)
//
#include <hip/hip_runtime.h>
#include <stdint.h>

#define BB 64
#define TT 2048
#define EE 256
#define HH 512
#define SLICE 128
#define HXN (BB * 2 * HH)   // u64 exchange slots

typedef unsigned long long u64;
typedef u64 u64x2 __attribute__((ext_vector_type(2)));
typedef float f32x4 __attribute__((ext_vector_type(4)));

__device__ __forceinline__ u64 pack_vt(float v, unsigned tag) {
    return ((u64)tag << 32) | (u64)__float_as_uint(v);
}
// plain stores land in the XCD's write-back L2 (vector L1 is write-through)
__device__ __forceinline__ void st_l2(u64* p, u64 v) {
    asm volatile("global_store_dwordx2 %0, %1, off" :: "v"((u64)p), "v"(v) : "memory");
}
__device__ __forceinline__ void st_l2_x4(u64* p, u64x2 v) {
    asm volatile("global_store_dwordx4 %0, %1, off" :: "v"((u64)p), "v"(v) : "memory");
}
// sc0 loads bypass L1 and re-read the shared XCD L2
__device__ __forceinline__ u64 ld_l2(const u64* p) {
    u64 v;
    asm volatile("global_load_dwordx2 %0, %1, off sc0\n\ts_waitcnt vmcnt(0)"
                 : "=v"(v) : "v"((u64)p) : "memory");
    return v;
}
__device__ __forceinline__ u64x2 ld_l2_x4(const u64* p) {
    u64x2 v;
    asm volatile("global_load_dwordx4 %0, %1, off sc0\n\ts_waitcnt vmcnt(0)"
                 : "=v"(v) : "v"((u64)p) : "memory");
    return v;
}

// 256 blocks (4/batch) x 256 threads (4 waves = 1 wave/SIMD, waves_per_eu(1,1)
// => 512-VGPR budget). Thread (rg=tid>>3, kg=tid&7) owns 4 rows x 64-k W_hh
// (64 f32x4) + 4 rows x 32-e W_ih (32 f32x4) = 384 register-resident floats.
// Per step: 24 rotation-swizzled ds_read_b128 + 384 fma -> 8-lane butterfly ->
// 2 tanh on kg<2 lanes -> dwordx4 publish via same-XCD L2 (agent fallback).
// Double-buffered lds_h/lds_x => ONE barrier per step.
__global__ __attribute__((amdgpu_flat_work_group_size(256, 256),
                          amdgpu_waves_per_eu(1, 1)))
void rnn_scan(const float* __restrict__ x,
              const int* __restrict__ lengths,
              const float* __restrict__ W_ih,
              const float* __restrict__ W_hh,
              const float* __restrict__ b_ih,
              const float* __restrict__ b_hh,
              const float* __restrict__ w_fc,
              const float* __restrict__ b_fc,
              float* __restrict__ out,   // [64] counts ++ [64][512] h_n
              u64* __restrict__ hx)      // [HXN] exchange ++ handshake slots
{
    const int b   = blockIdx.x & 63;
    const int s   = blockIdx.x >> 6;
    const int tid = threadIdx.x;
    const int rg  = tid >> 3;      // 0..31 (4 rows each)
    const int kg  = tid & 7;       // 0..7  (64-wide k slice)
    const int row0 = s * SLICE + rg * 4;

    __shared__ float lds_h[2][HH];
    __shared__ float lds_x[2][EE];
    __shared__ float lds_wf[HH];
    __shared__ int   sh_fast;

    // ---- weights into registers, pre-permuted for rotated LDS reads ----
    f32x4 whh[4][16];   // slot i holds k-subchunk (i+kg)&15 of the 64-wide slice
#pragma unroll
    for (int j = 0; j < 4; ++j)
#pragma unroll
        for (int i = 0; i < 16; ++i) {
            const int q = (i + kg) & 15;
            whh[j][i] = *(const f32x4*)&W_hh[(size_t)(row0 + j) * HH + kg * 64 + q * 4];
            asm volatile("" : "+v"(whh[j][i]));
        }
    f32x4 wih[4][8];    // slot i holds e-subchunk (i+kg)&7 of the 32-wide slice
#pragma unroll
    for (int j = 0; j < 4; ++j)
#pragma unroll
        for (int i = 0; i < 8; ++i) {
            const int q = (i + kg) & 7;
            wih[j][i] = *(const f32x4*)&W_ih[(size_t)(row0 + j) * EE + kg * 32 + q * 4];
            asm volatile("" : "+v"(wih[j][i]));
        }
    const int pr0 = row0 + (kg & 1) * 2;          // producer rows (kg<2 lanes)
    const float bs0 = b_ih[pr0] + b_hh[pr0];
    const float bs1 = b_ih[pr0 + 1] + b_hh[pr0 + 1];
    float bfc = 0.f;
    if (s == 0 && tid < 64) bfc = b_fc[0];
    lds_wf[tid]       = w_fc[tid];
    lds_wf[tid + 256] = w_fc[tid + 256];

    // ---- handshake: rendezvous (agent) -> probe L2 path -> agree (agent) ----
    u64* hxb = hx + (size_t)b * 2 * HH;
    if (tid == 0) {
        u64* pres = hx + HXN +       (size_t)b * 4;
        u64* prob = hx + HXN + 256 + (size_t)b * 4;
        u64* flag = hx + HXN + 512 + (size_t)b * 4;
        __hip_atomic_store(&pres[s], pack_vt(0.f, 0xA11A0u + (unsigned)s),
                           __ATOMIC_RELAXED, __HIP_MEMORY_SCOPE_AGENT);
        st_l2(&prob[s], pack_vt(0.f, 0xB22B0u + (unsigned)s));
        for (int q = 0; q < 4; ++q) {           // rendezvous: peers are live
            int g = 0; u64 v;
            do { v = __hip_atomic_load(&pres[q], __ATOMIC_RELAXED,
                                       __HIP_MEMORY_SCOPE_AGENT);
            } while ((unsigned)(v >> 32) != 0xA11A0u + (unsigned)q && ++g < (1 << 22));
        }
        int ok = 1;                              // probe fast-path visibility
        for (int q = 0; q < 4; ++q) {
            const unsigned want = 0xB22B0u + (unsigned)q;
            int g = 0; u64 v;
            do { v = ld_l2(&prob[q]); } while ((unsigned)(v >> 32) != want && ++g < 1024);
            if ((unsigned)(v >> 32) != want) { ok = 0; break; }
        }
        __hip_atomic_store(&flag[s], pack_vt(0.f, 0xC33C0u + (unsigned)(ok ? 1 : 0)),
                           __ATOMIC_RELAXED, __HIP_MEMORY_SCOPE_AGENT);
        int fastf = 1;
        for (int q = 0; q < 4; ++q) {
            int g = 0; unsigned got;
            do {
                u64 v = __hip_atomic_load(&flag[q], __ATOMIC_RELAXED,
                                          __HIP_MEMORY_SCOPE_AGENT);
                got = (unsigned)(v >> 32);
            } while ((got & ~1u) != 0xC33C0u && ++g < (1 << 22));
            if (got != 0xC33C1u) fastf = 0;
        }
        sh_fast = fastf;
    }

    const int len = lengths[b];
    const float* xrow = x + (size_t)b * TT * EE;

    lds_h[0][tid]       = 0.f;
    lds_h[0][tid + 256] = 0.f;
    if (tid < 64) *(f32x4*)&lds_x[0][tid * 4] = *(const f32x4*)&xrow[tid * 4];
    __syncthreads();
    const bool fastp = (sh_fast != 0);

    int count = 0;

#pragma unroll 1
    for (int t = 0; t < len; ++t) {
        const int p = t & 1;
        const int si = tid - 192;   // stagers: tid in [192,256)
        f32x4 xn = {0.f, 0.f, 0.f, 0.f};
        if (si >= 0 && t + 1 < TT)
            xn = *(const f32x4*)&xrow[(size_t)(t + 1) * EE + si * 4];

        // ---- register-blocked GEMV: 4 rows x (64 hk + 32 xe), rotated reads ----
        const float* hb = &lds_h[p][kg * 64];
        const float* xb = &lds_x[p][kg * 32];
        f32x4 a0 = {0.f,0.f,0.f,0.f}, a1 = a0, a2 = a0, a3 = a0;
#define FMA4(acc, w, v) \
        acc[0] = fmaf((w)[0], (v)[0], acc[0]); acc[1] = fmaf((w)[1], (v)[1], acc[1]); \
        acc[2] = fmaf((w)[2], (v)[2], acc[2]); acc[3] = fmaf((w)[3], (v)[3], acc[3]);
#pragma unroll
        for (int i = 0; i < 16; ++i) {
            f32x4 hv = *(const f32x4*)(hb + ((i + kg) & 15) * 4);
            FMA4(a0, whh[0][i], hv) FMA4(a1, whh[1][i], hv)
            FMA4(a2, whh[2][i], hv) FMA4(a3, whh[3][i], hv)
        }
#pragma unroll
        for (int i = 0; i < 8; ++i) {
            f32x4 xv = *(const f32x4*)(xb + ((i + kg) & 7) * 4);
            FMA4(a0, wih[0][i], xv) FMA4(a1, wih[1][i], xv)
            FMA4(a2, wih[2][i], xv) FMA4(a3, wih[3][i], xv)
        }
        float r0 = (a0[0] + a0[1]) + (a0[2] + a0[3]);
        float r1 = (a1[0] + a1[1]) + (a1[2] + a1[3]);
        float r2 = (a2[0] + a2[1]) + (a2[2] + a2[3]);
        float r3 = (a3[0] + a3[1]) + (a3[2] + a3[3]);
#pragma unroll
        for (int m = 1; m < 8; m <<= 1) {          // butterfly over 8 kg lanes
            r0 += __shfl_xor(r0, m); r1 += __shfl_xor(r1, m);
            r2 += __shfl_xor(r2, m); r3 += __shfl_xor(r3, m);
        }

        const unsigned tag = (unsigned)(t + 1);
        u64* slot = hxb + (size_t)p * HH;

        if (kg < 2) {   // producers: 2 rows each, 64 lanes -> 128 h values
            const float h0 = tanhf((kg ? r2 : r0) + bs0);
            const float h1 = tanhf((kg ? r3 : r1) + bs1);
            const int gi = pr0;   // row0 + kg*2
            *(float2*)&lds_h[p ^ 1][gi] = make_float2(h0, h1);
            if (fastp) {
                u64x2 v; v[0] = pack_vt(h0, tag); v[1] = pack_vt(h1, tag);
                st_l2_x4(&slot[gi], v);
            } else {
                __hip_atomic_store(&slot[gi], pack_vt(h0, tag),
                                   __ATOMIC_RELAXED, __HIP_MEMORY_SCOPE_AGENT);
                __hip_atomic_store(&slot[gi + 1], pack_vt(h1, tag),
                                   __ATOMIC_RELAXED, __HIP_MEMORY_SCOPE_AGENT);
            }
        }

        if (tid < 192) {   // pollers: 3 remote slices as 2-slot pairs
            const int sp = (s + 1 + (tid >> 6)) & 3;
            const int gi = sp * SLICE + (tid & 63) * 2;
            u64 v0 = 0, v1 = 0;
            if (fastp) {
                u64x2 v; int g = 0;
                do { v = ld_l2_x4(&slot[gi]); }
                while (((unsigned)(v[0] >> 32) != tag ||
                        (unsigned)(v[1] >> 32) != tag) && ++g < (1 << 12));
                v0 = v[0]; v1 = v[1];
            }
            if ((unsigned)(v0 >> 32) != tag || (unsigned)(v1 >> 32) != tag) {
                int g = 0;
                do { v0 = __hip_atomic_load(&slot[gi], __ATOMIC_RELAXED,
                                            __HIP_MEMORY_SCOPE_AGENT);
                } while ((unsigned)(v0 >> 32) != tag && ++g < (1 << 22));
                g = 0;
                do { v1 = __hip_atomic_load(&slot[gi + 1], __ATOMIC_RELAXED,
                                            __HIP_MEMORY_SCOPE_AGENT);
                } while ((unsigned)(v1 >> 32) != tag && ++g < (1 << 22));
            }
            *(float2*)&lds_h[p ^ 1][gi] =
                make_float2(__uint_as_float((unsigned)v0),
                            __uint_as_float((unsigned)v1));
        } else if (t + 1 < TT) {   // stagers: commit prefetched x row
            *(f32x4*)&lds_x[p ^ 1][si * 4] = xn;
        }
        __syncthreads();   // h_t complete in lds_h[p^1]

        if (s == 0) {
            if (tid < 64) {   // fc logit count (wave 0)
                const f32x4* h4  = (const f32x4*)lds_h[p ^ 1];
                const f32x4* wf4 = (const f32x4*)lds_wf;
                f32x4 v0 = h4[tid * 2], v1 = h4[tid * 2 + 1];
                f32x4 w0 = wf4[tid * 2], w1 = wf4[tid * 2 + 1];
                float pd = v0[0]*w0[0] + v0[1]*w0[1] + v0[2]*w0[2] + v0[3]*w0[3]
                         + v1[0]*w1[0] + v1[1]*w1[1] + v1[2]*w1[2] + v1[3]*w1[3];
#pragma unroll
                for (int m = 1; m < 64; m <<= 1) pd += __shfl_xor(pd, m);
                if (tid == 0 && (pd + bfc) > 0.f) count++;
            }
            if (t == len - 1) {
                *(float2*)&out[64 + b * HH + tid * 2] =
                    *(const float2*)&lds_h[p ^ 1][tid * 2];
            }
        }
    }

    if (s == 0 && tid == 0) out[b] = (float)count;
}

extern "C" void kernel_launch(void* const* d_in, const int* in_sizes, int n_in,
                              void* d_out, int out_size, void* d_ws, size_t ws_size,
                              hipStream_t stream) {
    const float* x       = (const float*)d_in[0];
    const int*   lengths = (const int*)  d_in[1];
    const float* W_ih    = (const float*)d_in[2];
    const float* W_hh    = (const float*)d_in[3];
    const float* b_ih    = (const float*)d_in[4];
    const float* b_hh    = (const float*)d_in[5];
    const float* w_fc    = (const float*)d_in[6];
    const float* b_fc    = (const float*)d_in[7];
    float* out = (float*)d_out;
    u64*   hx  = (u64*)d_ws;   // 512KB exchange + 6KB handshake

    hipLaunchKernelGGL(rnn_scan, dim3(BB * 4), dim3(256), 0, stream,
                       x, lengths, W_ih, W_hh, b_ih, b_hh, w_fc, b_fc, out, hx);
}

// Round 6
// 6666.738 us; speedup vs baseline: 108.8107x; 108.8107x over previous
//
#include <hip/hip_runtime.h>
#include <stdint.h>

#define BB 64
#define TT 2048
#define EE 256
#define HH 512
#define SLICE 128
#define HXN (BB * 2 * HH)   // u64 exchange slots

typedef unsigned long long u64;
typedef float f32x4 __attribute__((ext_vector_type(4)));

__device__ __forceinline__ u64 pack_vt(float v, unsigned tag) {
    return ((u64)tag << 32) | (u64)__float_as_uint(v);
}

// 256 blocks (4/batch) x 256 threads = 4 waves = 1 wave/SIMD (waves_per_eu(1,1))
// => 512-reg unified VGPR+AGPR budget per wave.
// Thread (rg=tid>>3, kg=tid&7) owns 4 rows x 64-k W_hh (64 f32x4, pinned in
// AGPRs via "+a" — exactly 256 accum regs) and 4 rows x 32-e W_ih (32 f32x4,
// pinned in arch VGPRs via "+v" — 128 regs). CDNA4 VALU reads AGPRs directly
// (unified file), so the FMA loop runs register-resident: NO weight restream,
// NO scratch. LDS h/x reads rotation-swizzled; weights pre-permuted to match.
// Exchange: agent-scope tagged u64 atomics (the protocol proven in rounds 1-2);
// the st_l2/sc0 "fast path" is removed — it never achieved timely cross-XCD
// visibility and burned its poll bound every step (rounds 3-5, ~730 ms).
__global__ __attribute__((amdgpu_flat_work_group_size(256, 256),
                          amdgpu_waves_per_eu(1, 1)))
void rnn_scan(const float* __restrict__ x,
              const int* __restrict__ lengths,
              const float* __restrict__ W_ih,
              const float* __restrict__ W_hh,
              const float* __restrict__ b_ih,
              const float* __restrict__ b_hh,
              const float* __restrict__ w_fc,
              const float* __restrict__ b_fc,
              float* __restrict__ out,   // [64] counts ++ [64][512] h_n
              u64* __restrict__ hx)      // [HXN] exchange slots
{
    const int b   = blockIdx.x & 63;
    const int s   = blockIdx.x >> 6;
    const int tid = threadIdx.x;
    const int rg  = tid >> 3;      // 0..31 (4 rows each)
    const int kg  = tid & 7;       // 0..7  (64-wide k slice)
    const int row0 = s * SLICE + rg * 4;

    __shared__ float lds_h[2][HH];
    __shared__ float lds_x[2][EE];
    __shared__ float lds_wf[HH];

    // ---- W_hh into AGPRs (pre-permuted for rotated LDS reads) ----
    f32x4 whh[4][16];   // slot i holds k-subchunk (i+kg)&15 of the 64-wide slice
#pragma unroll
    for (int j = 0; j < 4; ++j)
#pragma unroll
        for (int i = 0; i < 16; ++i) {
            const int q = (i + kg) & 15;
            whh[j][i] = *(const f32x4*)&W_hh[(size_t)(row0 + j) * HH + kg * 64 + q * 4];
            asm volatile("" : "+a"(whh[j][i]));   // pin in accum file
        }
    // ---- W_ih into arch VGPRs ----
    f32x4 wih[4][8];    // slot i holds e-subchunk (i+kg)&7 of the 32-wide slice
#pragma unroll
    for (int j = 0; j < 4; ++j)
#pragma unroll
        for (int i = 0; i < 8; ++i) {
            const int q = (i + kg) & 7;
            wih[j][i] = *(const f32x4*)&W_ih[(size_t)(row0 + j) * EE + kg * 32 + q * 4];
            asm volatile("" : "+v"(wih[j][i]));   // pin in arch file
        }
    const int pr0 = row0 + (kg & 1) * 2;          // producer rows (kg<2 lanes)
    const float bs0 = b_ih[pr0] + b_hh[pr0];
    const float bs1 = b_ih[pr0 + 1] + b_hh[pr0 + 1];
    float bfc = 0.f;
    if (s == 0 && tid < 64) bfc = b_fc[0];
    lds_wf[tid]       = w_fc[tid];
    lds_wf[tid + 256] = w_fc[tid + 256];

    const int len = lengths[b];
    const float* xrow = x + (size_t)b * TT * EE;
    u64* hxb = hx + (size_t)b * 2 * HH;   // [2][512] parity slots for this batch

    lds_h[0][tid]       = 0.f;
    lds_h[0][tid + 256] = 0.f;
    if (tid < 64) *(f32x4*)&lds_x[0][tid * 4] = *(const f32x4*)&xrow[tid * 4];
    __syncthreads();

    int count = 0;

#pragma unroll 1
    for (int t = 0; t < len; ++t) {
        const int p = t & 1;
        const int si = tid - 192;   // stagers: tid in [192,256)
        f32x4 xn = {0.f, 0.f, 0.f, 0.f};
        if (si >= 0 && t + 1 < TT)
            xn = *(const f32x4*)&xrow[(size_t)(t + 1) * EE + si * 4];

        // ---- register-blocked GEMV: 4 rows x (64 hk + 32 xe), rotated reads ----
        const float* hb = &lds_h[p][kg * 64];
        const float* xb = &lds_x[p][kg * 32];
        f32x4 a0 = {0.f,0.f,0.f,0.f}, a1 = a0, a2 = a0, a3 = a0;
#define FMA4(acc, w, v) \
        acc[0] = fmaf((w)[0], (v)[0], acc[0]); acc[1] = fmaf((w)[1], (v)[1], acc[1]); \
        acc[2] = fmaf((w)[2], (v)[2], acc[2]); acc[3] = fmaf((w)[3], (v)[3], acc[3]);
#pragma unroll
        for (int i = 0; i < 16; ++i) {
            f32x4 hv = *(const f32x4*)(hb + ((i + kg) & 15) * 4);
            FMA4(a0, whh[0][i], hv) FMA4(a1, whh[1][i], hv)
            FMA4(a2, whh[2][i], hv) FMA4(a3, whh[3][i], hv)
        }
#pragma unroll
        for (int i = 0; i < 8; ++i) {
            f32x4 xv = *(const f32x4*)(xb + ((i + kg) & 7) * 4);
            FMA4(a0, wih[0][i], xv) FMA4(a1, wih[1][i], xv)
            FMA4(a2, wih[2][i], xv) FMA4(a3, wih[3][i], xv)
        }
        float r0 = (a0[0] + a0[1]) + (a0[2] + a0[3]);
        float r1 = (a1[0] + a1[1]) + (a1[2] + a1[3]);
        float r2 = (a2[0] + a2[1]) + (a2[2] + a2[3]);
        float r3 = (a3[0] + a3[1]) + (a3[2] + a3[3]);
#pragma unroll
        for (int m = 1; m < 8; m <<= 1) {          // butterfly over 8 kg lanes
            r0 += __shfl_xor(r0, m); r1 += __shfl_xor(r1, m);
            r2 += __shfl_xor(r2, m); r3 += __shfl_xor(r3, m);
        }

        const unsigned tag = (unsigned)(t + 1);
        u64* slot = hxb + (size_t)p * HH;

        if (kg < 2) {   // producers: 2 rows each, 64 lanes -> 128 h values
            const float h0 = tanhf((kg ? r2 : r0) + bs0);
            const float h1 = tanhf((kg ? r3 : r1) + bs1);
            const int gi = pr0;   // row0 + kg*2
            *(float2*)&lds_h[p ^ 1][gi] = make_float2(h0, h1);
            __hip_atomic_store(&slot[gi], pack_vt(h0, tag),
                               __ATOMIC_RELAXED, __HIP_MEMORY_SCOPE_AGENT);
            __hip_atomic_store(&slot[gi + 1], pack_vt(h1, tag),
                               __ATOMIC_RELAXED, __HIP_MEMORY_SCOPE_AGENT);
        }

        if (tid < 192) {   // pollers: 3 remote slices, 2 values each
            const int sp = (s + 1 + (tid >> 6)) & 3;
            const int gi = sp * SLICE + (tid & 63) * 2;
            u64 v0, v1;
            int g = 0;
            do { v0 = __hip_atomic_load(&slot[gi], __ATOMIC_RELAXED,
                                        __HIP_MEMORY_SCOPE_AGENT);
            } while ((unsigned)(v0 >> 32) != tag && ++g < (1 << 22));
            g = 0;
            do { v1 = __hip_atomic_load(&slot[gi + 1], __ATOMIC_RELAXED,
                                        __HIP_MEMORY_SCOPE_AGENT);
            } while ((unsigned)(v1 >> 32) != tag && ++g < (1 << 22));
            *(float2*)&lds_h[p ^ 1][gi] =
                make_float2(__uint_as_float((unsigned)v0),
                            __uint_as_float((unsigned)v1));
        } else if (t + 1 < TT) {   // stagers: commit prefetched x row
            *(f32x4*)&lds_x[p ^ 1][si * 4] = xn;
        }
        __syncthreads();   // h_t complete in lds_h[p^1]

        if (s == 0) {
            if (tid < 64) {   // fc logit count (wave 0)
                const f32x4* h4  = (const f32x4*)lds_h[p ^ 1];
                const f32x4* wf4 = (const f32x4*)lds_wf;
                f32x4 v0 = h4[tid * 2], v1 = h4[tid * 2 + 1];
                f32x4 w0 = wf4[tid * 2], w1 = wf4[tid * 2 + 1];
                float pd = v0[0]*w0[0] + v0[1]*w0[1] + v0[2]*w0[2] + v0[3]*w0[3]
                         + v1[0]*w1[0] + v1[1]*w1[1] + v1[2]*w1[2] + v1[3]*w1[3];
#pragma unroll
                for (int m = 1; m < 64; m <<= 1) pd += __shfl_xor(pd, m);
                if (tid == 0 && (pd + bfc) > 0.f) count++;
            }
            if (t == len - 1) {
                *(float2*)&out[64 + b * HH + tid * 2] =
                    *(const float2*)&lds_h[p ^ 1][tid * 2];
            }
        }
    }

    if (s == 0 && tid == 0) out[b] = (float)count;
}

extern "C" void kernel_launch(void* const* d_in, const int* in_sizes, int n_in,
                              void* d_out, int out_size, void* d_ws, size_t ws_size,
                              hipStream_t stream) {
    const float* x       = (const float*)d_in[0];
    const int*   lengths = (const int*)  d_in[1];
    const float* W_ih    = (const float*)d_in[2];
    const float* W_hh    = (const float*)d_in[3];
    const float* b_ih    = (const float*)d_in[4];
    const float* b_hh    = (const float*)d_in[5];
    const float* w_fc    = (const float*)d_in[6];
    const float* b_fc    = (const float*)d_in[7];
    float* out = (float*)d_out;
    u64*   hx  = (u64*)d_ws;   // 512KB exchange

    hipLaunchKernelGGL(rnn_scan, dim3(BB * 4), dim3(256), 0, stream,
                       x, lengths, W_ih, W_hh, b_ih, b_hh, w_fc, b_fc, out, hx);
}